// Round 4
// baseline (249.931 us; speedup 1.0000x reference)
//
#include <hip/hip_runtime.h>

#define LOG2E 1.4426950408889634f
#define MAGIC 0x5CA1AB1Eu

typedef __bf16 bf16x8 __attribute__((ext_vector_type(8)));
typedef float  f32x4  __attribute__((ext_vector_type(4)));

__device__ inline unsigned short f2bf(float f){
  unsigned u = __float_as_uint(f);
  unsigned r = u + 0x7FFFu + ((u >> 16) & 1u);   // RNE; inputs finite
  return (unsigned short)(r >> 16);
}
__device__ inline unsigned pack2(float lo, float hi){
  return (unsigned)f2bf(lo) | ((unsigned)f2bf(hi) << 16);
}

// ONE kernel, grid 256 x 1024 thr (16 waves), 1 block/CU (co-resident by construction).
// Phase 1: K-split GEMM  P[ks][256][1024] = x[:,ks*256:+256] @ W[ks*256:+256,:]
//   block bx -> (mt = bx&3, nt = (bx>>2)&15, ks = bx>>6); 64x64 tile, K-chunk 256.
// Grid barrier: device-fence + per-block MAGIC slot + wave-0 spin (slots live in
//   d_ws, re-poisoned 0xAA != MAGIC before every launch -> no init dispatch needed).
// Phase 2: pair. block bx -> (b = bx>>2, jc = bx&3); identical math to R3 k_pair.
__global__ __launch_bounds__(1024) void k_fused(const float* __restrict__ X,
                                                const float* __restrict__ Wm,
                                                const float* __restrict__ bias,
                                                float* __restrict__ P,
                                                unsigned* __restrict__ slots,
                                                float* __restrict__ out){
  __shared__ union {
    struct { unsigned short As[64 * 72]; unsigned short Bs[64 * 72]; } g;
    struct { float L[256 * 16]; float red[16][64]; } p;
  } sm;

  const int bx = blockIdx.x;
  const int t = threadIdx.x;
  const int lane = t & 63, w = t >> 6;          // 16 waves
  const int r16 = lane & 15, quad = lane >> 4;

  // ---------------- Phase 1: GEMM ----------------
  {
    const int m0 = (bx & 3) * 64;
    const int n0 = ((bx >> 2) & 15) * 64;
    const int k0 = (bx >> 6) * 256;

    // staging maps (1024 threads)
    const int arow = t >> 4, akq = t & 15;      // A: row, 4-float chunk
    const int bn = t & 63, bkq = t >> 6;        // B: n-col, 4-krow chunk
    const float* ap = X + (size_t)(m0 + arow) * 1024 + k0 + akq * 4;
    const float* bp = Wm + (size_t)(k0 + bkq * 4) * 1024 + n0 + bn;

    const int mw = w & 3, nw = w >> 2;          // wave's 16x16 tile
    f32x4 acc = {0.f, 0.f, 0.f, 0.f};

    float4 pa = *(const float4*)ap;
    float pb0 = bp[0], pb1 = bp[1024], pb2 = bp[2048], pb3 = bp[3072];

    #pragma unroll
    for (int kt = 0; kt < 256; kt += 64){
      __syncthreads();                          // prev iter ds_reads done
      { // A: 4 floats -> 4 bf16, 8B store
        uint2 ua; ua.x = pack2(pa.x, pa.y); ua.y = pack2(pa.z, pa.w);
        *(uint2*)(&sm.g.As[arow * 72 + akq * 4]) = ua;
      }
      { // B: 4 k-adjacent floats -> 4 bf16 at [n][k], XOR-chunk swizzled
        uint2 ub; ub.x = pack2(pb0, pb1); ub.y = pack2(pb2, pb3);
        const int cw = (bkq >> 1) ^ ((bn >> 3) & 7);
        *(uint2*)(&sm.g.Bs[bn * 72 + cw * 8 + (bkq & 1) * 4]) = ub;
      }
      __syncthreads();
      if (kt < 192){                            // prefetch next k-tile
        pa = *(const float4*)(ap + kt + 64);
        const float* nb_ = bp + (size_t)(kt + 64) * 1024;
        pb0 = nb_[0]; pb1 = nb_[1024]; pb2 = nb_[2048]; pb3 = nb_[3072];
      }
      #pragma unroll
      for (int kk = 0; kk < 2; ++kk){
        bf16x8 a = *(const bf16x8*)(&sm.g.As[(mw * 16 + r16) * 72 + kk * 32 + quad * 8]);
        const int nb = nw * 16 + r16;
        const int c = kk * 4 + quad;
        bf16x8 b = *(const bf16x8*)(&sm.g.Bs[nb * 72 + ((c ^ ((nb >> 3) & 7)) * 8)]);
        acc = __builtin_amdgcn_mfma_f32_16x16x32_bf16(a, b, acc, 0, 0, 0);
      }
    }
    // C/D layout (verified): col = lane&15, row = (lane>>4)*4 + reg
    float* Pz = P + (size_t)(bx >> 6) * 256 * 1024;
    #pragma unroll
    for (int r = 0; r < 4; ++r){
      const int row = m0 + mw * 16 + quad * 4 + r;
      const int col = n0 + nw * 16 + r16;
      Pz[(size_t)row * 1024 + col] = acc[r];
    }
  }

  // ---------------- Grid barrier ----------------
  __threadfence();                              // release P stores (device scope)
  __syncthreads();
  if (t == 0)
    __hip_atomic_store(&slots[bx], MAGIC, __ATOMIC_RELEASE, __HIP_MEMORY_SCOPE_AGENT);
  if (t < 64){                                  // wave 0 polls 4 slots per lane
    bool done;
    do {
      unsigned v0 = __hip_atomic_load(&slots[t * 4 + 0], __ATOMIC_ACQUIRE, __HIP_MEMORY_SCOPE_AGENT);
      unsigned v1 = __hip_atomic_load(&slots[t * 4 + 1], __ATOMIC_ACQUIRE, __HIP_MEMORY_SCOPE_AGENT);
      unsigned v2 = __hip_atomic_load(&slots[t * 4 + 2], __ATOMIC_ACQUIRE, __HIP_MEMORY_SCOPE_AGENT);
      unsigned v3 = __hip_atomic_load(&slots[t * 4 + 3], __ATOMIC_ACQUIRE, __HIP_MEMORY_SCOPE_AGENT);
      done = (v0 == MAGIC) & (v1 == MAGIC) & (v2 == MAGIC) & (v3 == MAGIC);
    } while (__ballot(done) != ~0ull);
  }
  __syncthreads();
  __threadfence();                              // acquire side, belt-and-braces

  // ---------------- Phase 2: pair ----------------
  {
    const int b = bx >> 2, jc = bx & 3;

    { // stage + reduce the 4 K-split partials: thread -> one float4 of L
      const int i = t >> 2, q = t & 3;
      const float* base = P + (size_t)i * 1024 + b * 16 + q * 4;
      float4 s0 = *(const float4*)(base);
      float4 s1 = *(const float4*)(base + 256 * 1024);
      float4 s2 = *(const float4*)(base + 512 * 1024);
      float4 s3 = *(const float4*)(base + 768 * 1024);
      float4 r;
      r.x = (s0.x + s1.x) + (s2.x + s3.x);
      r.y = (s0.y + s1.y) + (s2.y + s3.y);
      r.z = (s0.z + s1.z) + (s2.z + s3.z);
      r.w = (s0.w + s1.w) + (s2.w + s3.w);
      *(float4*)(&sm.p.L[i * 16 + q * 4]) = r;
    }
    __syncthreads();

    const int j = jc * 64 + lane;
    float oj[16];
    #pragma unroll
    for (int q = 0; q < 4; ++q){
      float4 v = *(const float4*)(&sm.p.L[j * 16 + q * 4]);
      oj[q*4+0] = v.x; oj[q*4+1] = v.y; oj[q*4+2] = v.z; oj[q*4+3] = v.w;
    }

    float acc = 0.f;
    const int i0 = w * 16;
    #pragma unroll 4
    for (int ii = i0; ii < i0 + 16; ++ii){
      const float4* fr = (const float4*)(&sm.p.L[ii * 16]);  // wave-uniform -> broadcast
      float4 f0 = fr[0], f1 = fr[1], f2 = fr[2], f3 = fr[3];
      float p0 = fabsf(oj[0]  - f0.x) + fabsf(oj[1]  - f0.y)
               + fabsf(oj[2]  - f0.z) + fabsf(oj[3]  - f0.w);
      float p1 = fabsf(oj[4]  - f1.x) + fabsf(oj[5]  - f1.y)
               + fabsf(oj[6]  - f1.z) + fabsf(oj[7]  - f1.w);
      float p2 = fabsf(oj[8]  - f2.x) + fabsf(oj[9]  - f2.y)
               + fabsf(oj[10] - f2.z) + fabsf(oj[11] - f2.w);
      float p3 = fabsf(oj[12] - f3.x) + fabsf(oj[13] - f3.y)
               + fabsf(oj[14] - f3.z) + fabsf(oj[15] - f3.w);
      acc += exp2f(-LOG2E * ((p0 + p1) + (p2 + p3)));
    }
    sm.p.red[w][lane] = acc;
    __syncthreads();
    if (w == 0){
      float tot = 0.f;
      #pragma unroll
      for (int ww = 0; ww < 16; ++ww) tot += sm.p.red[ww][lane];
      out[(size_t)j * 64 + b] = tot + bias[b];
    }
  }
}

extern "C" void kernel_launch(void* const* d_in, const int* in_sizes, int n_in,
                              void* d_out, int out_size, void* d_ws, size_t ws_size,
                              hipStream_t stream){
  const float* x    = (const float*)d_in[0];   // [256][1024]
  const float* W    = (const float*)d_in[1];   // [1024][1024] k-major
  const float* bias = (const float*)d_in[2];   // [64]
  float* out = (float*)d_out;                  // [256][64]
  float* P   = (float*)d_ws;                   // 4 MB: partials [4][256][1024]
  unsigned* slots = (unsigned*)(P + 4 * 256 * 1024);  // 1 KB barrier slots (poisoned 0xAA)

  k_fused<<<256, 1024, 0, stream>>>(x, W, bias, P, slots, out);
}

// Round 5
// 142.824 us; speedup vs baseline: 1.7499x; 1.7499x over previous
//
#include <hip/hip_runtime.h>

#define LOG2E 1.4426950408889634f
#define MAGIC 0x5CA1AB1Eu

typedef __bf16 bf16x8 __attribute__((ext_vector_type(8)));
typedef float  f32x4  __attribute__((ext_vector_type(4)));

#define TSTR 76            // GEMM LDS tile row stride (shorts): 152 B = 38 banks -> <=2-way reads
#define LSTR 20            // pair LDS row stride (floats): 80 B, 16B-aligned, bank stride 20

__device__ inline unsigned short f2bf(float f){
  unsigned u = __float_as_uint(f);
  unsigned r = u + 0x7FFFu + ((u >> 16) & 1u);   // RNE; inputs finite
  return (unsigned short)(r >> 16);
}
__device__ inline unsigned pack2(float lo, float hi){
  return (unsigned)f2bf(lo) | ((unsigned)f2bf(hi) << 16);
}

// ONE kernel, grid 256 x 1024 thr (16 waves), 1 block/CU (co-resident by construction).
// Phase 1: K-split GEMM  P[ks][256][1024] = x[:,ks*256:+256] @ W[ks*256:+256,:]
// Barrier: per-block MAGIC slot (0xAA-poison != MAGIC -> no init needed).
//   Release: one fence + relaxed store per block. Poll: wave 0, RELAXED loads
//   (no per-iteration invalidate!) + s_sleep backoff; ONE acquire fence at exit.
// Phase 2: pair, identical math to R3.
__global__ __launch_bounds__(1024) void k_fused(const float* __restrict__ X,
                                                const float* __restrict__ Wm,
                                                const float* __restrict__ bias,
                                                float* __restrict__ P,
                                                unsigned* __restrict__ slots,
                                                float* __restrict__ out){
  __shared__ union {
    struct { unsigned short As[64 * TSTR]; unsigned short Bs[64 * TSTR]; } g;
    struct { float L[256 * LSTR]; float red[16][64]; } p;
  } sm;

  const int bx = blockIdx.x;
  const int t = threadIdx.x;
  const int lane = t & 63, w = t >> 6;          // 16 waves
  const int r16 = lane & 15, quad = lane >> 4;

  // ---------------- Phase 1: GEMM ----------------
  {
    const int m0 = (bx & 3) * 64;
    const int n0 = ((bx >> 2) & 15) * 64;
    const int k0 = (bx >> 6) * 256;

    const int arow = t >> 4, akq = t & 15;      // A: row, 4-float k-chunk
    const int bn = t & 63, bkq = t >> 6;        // B: n-col, 4-krow chunk
    const float* ap = X + (size_t)(m0 + arow) * 1024 + k0 + akq * 4;
    const float* bp = Wm + (size_t)(k0 + bkq * 4) * 1024 + n0 + bn;

    const int mw = w & 3, nw = w >> 2;          // wave's 16x16 tile
    f32x4 acc = {0.f, 0.f, 0.f, 0.f};

    float4 pa = *(const float4*)ap;
    float pb0 = bp[0], pb1 = bp[1024], pb2 = bp[2048], pb3 = bp[3072];

    #pragma unroll
    for (int kt = 0; kt < 256; kt += 64){
      __syncthreads();                          // prev iter ds_reads done
      { // A: 4 floats -> 4 bf16, 8B store (contiguous within 16-lane row)
        uint2 ua; ua.x = pack2(pa.x, pa.y); ua.y = pack2(pa.z, pa.w);
        *(uint2*)(&sm.g.As[arow * TSTR + akq * 4]) = ua;
      }
      { // B: 4 k-adjacent floats -> 4 bf16 at [n][k]
        uint2 ub; ub.x = pack2(pb0, pb1); ub.y = pack2(pb2, pb3);
        *(uint2*)(&sm.g.Bs[bn * TSTR + bkq * 4]) = ub;
      }
      __syncthreads();
      if (kt < 192){                            // prefetch next k-tile
        pa = *(const float4*)(ap + kt + 64);
        const float* nb_ = bp + (size_t)(kt + 64) * 1024;
        pb0 = nb_[0]; pb1 = nb_[1024]; pb2 = nb_[2048]; pb3 = nb_[3072];
      }
      #pragma unroll
      for (int kk = 0; kk < 2; ++kk){
        const int ko = kk * 32 + quad * 8;
        bf16x8 a = *(const bf16x8*)(&sm.g.As[(mw * 16 + r16) * TSTR + ko]);
        bf16x8 b = *(const bf16x8*)(&sm.g.Bs[(nw * 16 + r16) * TSTR + ko]);
        acc = __builtin_amdgcn_mfma_f32_16x16x32_bf16(a, b, acc, 0, 0, 0);
      }
    }
    // C/D layout (verified): col = lane&15, row = (lane>>4)*4 + reg
    float* Pz = P + (size_t)(bx >> 6) * 256 * 1024;
    #pragma unroll
    for (int r = 0; r < 4; ++r){
      const int row = m0 + mw * 16 + quad * 4 + r;
      const int col = n0 + nw * 16 + r16;
      Pz[(size_t)row * 1024 + col] = acc[r];
    }
  }

  // ---------------- Grid barrier ----------------
  __syncthreads();
  if (t == 0){
    __threadfence();                            // release P stores
    __hip_atomic_store(&slots[bx], MAGIC, __ATOMIC_RELAXED, __HIP_MEMORY_SCOPE_AGENT);
  }
  if (t < 64){                                  // wave 0 polls, relaxed loads only
    for (;;){
      unsigned v0 = __hip_atomic_load(&slots[t * 4 + 0], __ATOMIC_RELAXED, __HIP_MEMORY_SCOPE_AGENT);
      unsigned v1 = __hip_atomic_load(&slots[t * 4 + 1], __ATOMIC_RELAXED, __HIP_MEMORY_SCOPE_AGENT);
      unsigned v2 = __hip_atomic_load(&slots[t * 4 + 2], __ATOMIC_RELAXED, __HIP_MEMORY_SCOPE_AGENT);
      unsigned v3 = __hip_atomic_load(&slots[t * 4 + 3], __ATOMIC_RELAXED, __HIP_MEMORY_SCOPE_AGENT);
      bool done = (v0 == MAGIC) & (v1 == MAGIC) & (v2 == MAGIC) & (v3 == MAGIC);
      if (__ballot(done) == ~0ull) break;
      __builtin_amdgcn_s_sleep(2);              // back off the fabric
    }
  }
  __syncthreads();
  __threadfence();                              // ONE acquire fence for P reads

  // ---------------- Phase 2: pair ----------------
  {
    const int b = bx >> 2, jc = bx & 3;

    { // stage + reduce the 4 K-split partials: thread -> one float4 of L
      const int i = t >> 2, q = t & 3;
      const float* base = P + (size_t)i * 1024 + b * 16 + q * 4;
      float4 s0 = *(const float4*)(base);
      float4 s1 = *(const float4*)(base + 256 * 1024);
      float4 s2 = *(const float4*)(base + 512 * 1024);
      float4 s3 = *(const float4*)(base + 768 * 1024);
      float4 r;
      r.x = (s0.x + s1.x) + (s2.x + s3.x);
      r.y = (s0.y + s1.y) + (s2.y + s3.y);
      r.z = (s0.z + s1.z) + (s2.z + s3.z);
      r.w = (s0.w + s1.w) + (s2.w + s3.w);
      *(float4*)(&sm.p.L[i * LSTR + q * 4]) = r;
    }
    __syncthreads();

    const int j = jc * 64 + lane;
    float oj[16];
    #pragma unroll
    for (int q = 0; q < 4; ++q){
      float4 v = *(const float4*)(&sm.p.L[j * LSTR + q * 4]);
      oj[q*4+0] = v.x; oj[q*4+1] = v.y; oj[q*4+2] = v.z; oj[q*4+3] = v.w;
    }

    float acc = 0.f;
    const int i0 = w * 16;
    #pragma unroll 4
    for (int ii = i0; ii < i0 + 16; ++ii){
      const float4* fr = (const float4*)(&sm.p.L[ii * LSTR]);  // wave-uniform -> broadcast
      float4 f0 = fr[0], f1 = fr[1], f2 = fr[2], f3 = fr[3];
      float p0 = fabsf(oj[0]  - f0.x) + fabsf(oj[1]  - f0.y)
               + fabsf(oj[2]  - f0.z) + fabsf(oj[3]  - f0.w);
      float p1 = fabsf(oj[4]  - f1.x) + fabsf(oj[5]  - f1.y)
               + fabsf(oj[6]  - f1.z) + fabsf(oj[7]  - f1.w);
      float p2 = fabsf(oj[8]  - f2.x) + fabsf(oj[9]  - f2.y)
               + fabsf(oj[10] - f2.z) + fabsf(oj[11] - f2.w);
      float p3 = fabsf(oj[12] - f3.x) + fabsf(oj[13] - f3.y)
               + fabsf(oj[14] - f3.z) + fabsf(oj[15] - f3.w);
      acc += exp2f(-LOG2E * ((p0 + p1) + (p2 + p3)));
    }
    sm.p.red[w][lane] = acc;
    __syncthreads();
    if (w == 0){
      float tot = 0.f;
      #pragma unroll
      for (int ww = 0; ww < 16; ++ww) tot += sm.p.red[ww][lane];
      out[(size_t)j * 64 + b] = tot + bias[b];
    }
  }
}

extern "C" void kernel_launch(void* const* d_in, const int* in_sizes, int n_in,
                              void* d_out, int out_size, void* d_ws, size_t ws_size,
                              hipStream_t stream){
  const float* x    = (const float*)d_in[0];   // [256][1024]
  const float* W    = (const float*)d_in[1];   // [1024][1024] k-major
  const float* bias = (const float*)d_in[2];   // [64]
  float* out = (float*)d_out;                  // [256][64]
  float* P   = (float*)d_ws;                   // 4 MB: partials [4][256][1024]
  unsigned* slots = (unsigned*)(P + 4 * 256 * 1024);  // 1 KB barrier slots (poisoned 0xAA)

  k_fused<<<256, 1024, 0, stream>>>(x, W, bias, P, slots, out);
}